// Round 11
// baseline (480.094 us; speedup 1.0000x reference)
//
#include <hip/hip_runtime.h>
#include <stdint.h>

// HyperLatticeBlock: B=2,S=1024,D=1024,L=48,K=4  (tokens T=2048)
// ABLATION ROUND: real pipeline (r10-identical) + 4 expert-kernel probe variants into scratch.
#define TT 2048
#define DD 1024
#define LL 48
#define SENT (LL * 256)   // sentinel selp row (zeroed)

typedef __attribute__((ext_vector_type(8))) short short8;
typedef __attribute__((ext_vector_type(4))) float f32x4;

static __device__ __forceinline__ unsigned int f2bf(float f) {
  union { float f; unsigned int u; } v; v.f = f;
  return (v.u + 0x7FFFu + ((v.u >> 16) & 1u)) >> 16;   // RNE f32->bf16 bits
}
static __device__ __forceinline__ unsigned int pack2(float a, float b) {
  return f2bf(a) | (f2bf(b) << 16);
}

#define LGKM0 do { asm volatile("s_waitcnt lgkmcnt(0)" ::: "memory"); \
                   __builtin_amdgcn_sched_barrier(0); } while (0)
#define BAR do { __builtin_amdgcn_s_barrier(); __builtin_amdgcn_sched_barrier(0); } while (0)

// ---------------- gate: logits fp32, top-4, softmax, bucket scatter + A-pack ----------------
__global__ __launch_bounds__(256) void k_gate(
    const float* __restrict__ x, const float* __restrict__ gw,
    unsigned short* __restrict__ xg, int* __restrict__ counts,
    float* __restrict__ bscore, int* __restrict__ tpos)
{
  __shared__ float xs[8][1024];
  __shared__ float lg[8][48];
  __shared__ int tp_s[32];
  const int tid = threadIdx.x;
  const int t0 = blockIdx.x * 8;
  for (int u = tid; u < 2048; u += 256) {
    int tok = u >> 8;
    int c = (u & 255) << 2;
    float4 v = *(const float4*)(x + (size_t)(t0 + tok) * DD + c);
    *(float4*)&xs[tok][c] = v;
  }
  __syncthreads();
  const int lane = tid & 63, wid = tid >> 6;
  for (int li = 0; li < 12; ++li) {
    const int l = wid + (li << 2);
    const float4* gp = (const float4*)(gw + (size_t)l * DD);
    float4 g0 = gp[lane], g1 = gp[lane + 64], g2 = gp[lane + 128], g3 = gp[lane + 192];
    for (int tok = 0; tok < 8; ++tok) {
      const float4* xp = (const float4*)&xs[tok][0];
      float4 a0 = xp[lane], a1 = xp[lane + 64], a2 = xp[lane + 128], a3 = xp[lane + 192];
      float s = a0.x*g0.x + a0.y*g0.y + a0.z*g0.z + a0.w*g0.w
              + a1.x*g1.x + a1.y*g1.y + a1.z*g1.z + a1.w*g1.w
              + a2.x*g2.x + a2.y*g2.y + a2.z*g2.z + a2.w*g2.w
              + a3.x*g3.x + a3.y*g3.y + a3.z*g3.z + a3.w*g3.w;
      #pragma unroll
      for (int off = 32; off; off >>= 1) s += __shfl_down(s, off);
      if (lane == 0) lg[tok][l] = s;
    }
  }
  __syncthreads();
  if (tid < 8) {
    const int tok = tid;
    float v[4]; int id[4];
    unsigned long long taken = 0ull;
    for (int k = 0; k < 4; ++k) {
      float best = -3.4e38f; int bi = 0;
      for (int l = 0; l < 48; ++l) {
        float cand = lg[tok][l];
        if (!((taken >> l) & 1ull) && cand > best) { best = cand; bi = l; }
      }
      taken |= (1ull << bi); v[k] = best; id[k] = bi;
    }
    float e1 = expf(v[1] - v[0]);
    float e2 = expf(v[2] - v[0]);
    float e3 = expf(v[3] - v[0]);
    float inv = 1.0f / (1.0f + e1 + e2 + e3);
    float sc[4] = { inv, e1*inv, e2*inv, e3*inv };
    for (int k = 0; k < 4; ++k) {
      int pos = atomicAdd(&counts[id[k]], 1);
      bscore[id[k] * TT + pos] = sc[k];
      int dst = (pos < 256) ? (id[k] * 256 + pos) : SENT;
      tp_s[tok * 4 + k] = dst;
      tpos[((t0 + tok) << 2) | k] = dst;
    }
  }
  __syncthreads();
  for (int g = 0; g < 32; ++g) {
    int dst = tp_s[g];
    if (dst == SENT) continue;
    const float* src = xs[g >> 2];
    float a0 = src[tid * 4], a1 = src[tid * 4 + 1], a2 = src[tid * 4 + 2], a3 = src[tid * 4 + 3];
    uint2 pk; pk.x = pack2(a0, a1); pk.y = pack2(a2, a3);
    *(uint2*)(xg + (size_t)dst * DD + tid * 4) = pk;
  }
}

// ---------------- expert GEMM template: BM=256, BN=256, BK=32, 512 thr (4m x 2n waves) ----------------
// V bits: 1=global LOADS, 2=LDS ops (BSTORE + ds_reads), 4=MFMA, 8=BARRIERS.
// Real kernel = <15,32> (identical to round-10). Probes run NIT=64 into scratch.
#define KI(i) (((i) & 31) * 32)
template<int V, int NIT>
__global__ __launch_bounds__(512, 1) void k_expert_t(
    const unsigned short* __restrict__ xg, const float* __restrict__ W,
    const int* __restrict__ counts, const float* __restrict__ bscore,
    float* __restrict__ outp)
{
  constexpr bool LOADS   = (V & 1) != 0;
  constexpr bool LDSOPS  = (V & 2) != 0;
  constexpr bool DOMFMA  = (V & 4) != 0;
  constexpr bool BARS    = (V & 8) != 0;
  constexpr bool FULLEPI = (V == 15) && (NIT == 32);

  const int bid = blockIdx.x;
  const int l = bid % LL;
  const int n0 = (bid / LL) * 256;
  const int ncnt = min(counts[l], 256);
  const int tid = threadIdx.x, lane = tid & 63, wid = tid >> 6;
  const int wr = wid & 3, wc = wid >> 2;       // 4m x 2n (wave tile 64 x 128)
  const int fr = lane & 15, fq = lane >> 4;

  __shared__ alignas(16) unsigned int Bs[2][16 * 264];   // 2 x 16.5 KB
  __shared__ float scs[256];
  if (tid < 256) scs[tid] = (tid < ncnt) ? bscore[l * TT + tid] : 0.f;

  const unsigned short* ap[4];
  #pragma unroll
  for (int m = 0; m < 4; ++m)
    ap[m] = xg + ((size_t)l << 18) + (size_t)(wr * 64 + m * 16 + fr) * DD + fq * 8;
  const int bp = tid >> 5, e0 = (tid & 31) << 3;
  const float* wsrc0 = W + (size_t)l * DD * DD + (size_t)(bp << 1) * DD + n0 + e0;
  const float* wsrc1 = wsrc0 + DD;

  f32x4 acc[4][8];
  #pragma unroll
  for (int m = 0; m < 4; ++m)
    #pragma unroll
    for (int n = 0; n < 8; ++n)
      #pragma unroll
      for (int j = 0; j < 4; ++j) acc[m][n][j] = 0.f;

  short8 af[2][4];
  float4 rw[2][4];
  if constexpr (!LOADS) {                 // synthetic operands for no-load probes
    short8 z;
    #pragma unroll
    for (int j = 0; j < 8; ++j) z[j] = (short)(tid + j * 37);
    #pragma unroll
    for (int p = 0; p < 2; ++p)
      #pragma unroll
      for (int m = 0; m < 4; ++m) af[p][m] = z;
    #pragma unroll
    for (int s = 0; s < 2; ++s)
      #pragma unroll
      for (int i = 0; i < 4; ++i)
        rw[s][i] = make_float4((float)tid, (float)(tid + 1), (float)(tid + 2), (float)(tid + 3));
  }

#define E_BLOAD(s, k0) do { if constexpr (LOADS) { \
    rw[s][0] = *(const float4*)(wsrc0 + (size_t)(k0) * DD); \
    rw[s][1] = *(const float4*)(wsrc0 + (size_t)(k0) * DD + 4); \
    rw[s][2] = *(const float4*)(wsrc1 + (size_t)(k0) * DD); \
    rw[s][3] = *(const float4*)(wsrc1 + (size_t)(k0) * DD + 4); } } while (0)

#define E_ALOAD(p, k0) do { if constexpr (LOADS) { \
    af[p][0] = *(const short8*)(ap[0] + (k0)); \
    af[p][1] = *(const short8*)(ap[1] + (k0)); \
    af[p][2] = *(const short8*)(ap[2] + (k0)); \
    af[p][3] = *(const short8*)(ap[3] + (k0)); \
    if constexpr (!DOMFMA) { \
      const int4* a0 = (const int4*)&af[p][0]; const int4* a1 = (const int4*)&af[p][1]; \
      const int4* a2 = (const int4*)&af[p][2]; const int4* a3 = (const int4*)&af[p][3]; \
      asm volatile("" :: "v"(a0->x),"v"(a0->y),"v"(a0->z),"v"(a0->w), \
                         "v"(a1->x),"v"(a1->y),"v"(a1->z),"v"(a1->w), \
                         "v"(a2->x),"v"(a2->y),"v"(a2->z),"v"(a2->w), \
                         "v"(a3->x),"v"(a3->y),"v"(a3->z),"v"(a3->w)); } \
  } } while (0)

#define E_BSTORE(buf, s) do { \
    if constexpr (LDSOPS) { \
      uint4 p0, p1; \
      p0.x = pack2(rw[s][0].x, rw[s][2].x); p0.y = pack2(rw[s][0].y, rw[s][2].y); \
      p0.z = pack2(rw[s][0].z, rw[s][2].z); p0.w = pack2(rw[s][0].w, rw[s][2].w); \
      p1.x = pack2(rw[s][1].x, rw[s][3].x); p1.y = pack2(rw[s][1].y, rw[s][3].y); \
      p1.z = pack2(rw[s][1].z, rw[s][3].z); p1.w = pack2(rw[s][1].w, rw[s][3].w); \
      *(uint4*)&Bs[buf][bp * 264 + e0]     = p0; \
      *(uint4*)&Bs[buf][bp * 264 + e0 + 4] = p1; \
    } else if constexpr (LOADS) { \
      asm volatile("" :: "v"(rw[s][0].x),"v"(rw[s][0].y),"v"(rw[s][0].z),"v"(rw[s][0].w), \
                         "v"(rw[s][1].x),"v"(rw[s][1].y),"v"(rw[s][1].z),"v"(rw[s][1].w), \
                         "v"(rw[s][2].x),"v"(rw[s][2].y),"v"(rw[s][2].z),"v"(rw[s][2].w), \
                         "v"(rw[s][3].x),"v"(rw[s][3].y),"v"(rw[s][3].z),"v"(rw[s][3].w)); \
    } } while (0)

#define E_COMPUTE(buf, p) do { \
    _Pragma("unroll") for (int n = 0; n < 8; ++n) { \
      short8 bf; \
      if constexpr (LDSOPS) { \
        const unsigned int* Bb = Bs[buf]; \
        const int e = wc * 128 + n * 16 + fr; \
        uint4 q; \
        q.x = Bb[(fq * 4 + 0) * 264 + e]; q.y = Bb[(fq * 4 + 1) * 264 + e]; \
        q.z = Bb[(fq * 4 + 2) * 264 + e]; q.w = Bb[(fq * 4 + 3) * 264 + e]; \
        if constexpr (!DOMFMA) { asm volatile("" :: "v"(q.x),"v"(q.y),"v"(q.z),"v"(q.w)); } \
        bf = *(short8*)&q; \
      } else { \
        bf = af[p][n & 3]; \
      } \
      if constexpr (DOMFMA) { \
        _Pragma("unroll") for (int m = 0; m < 4; ++m) \
          acc[m][n] = __builtin_amdgcn_mfma_f32_16x16x32_bf16(af[p][m], bf, acc[m][n], 0, 0, 0); \
      } \
    } } while (0)

#define SYNC do { if constexpr (BARS) { LGKM0; BAR; } } while (0)

  // prologue
  E_BLOAD(0, KI(0)); E_BLOAD(1, KI(1));
  E_ALOAD(0, KI(0));
  E_BSTORE(0, 0);
  SYNC;
  // steady
  for (int t = 0; t < NIT - 2; t += 2) {
    E_BLOAD(0, KI(t + 2));
    E_ALOAD(1, KI(t + 1));
    E_COMPUTE(0, 0);
    SYNC;
    E_BSTORE(1, 1);
    SYNC;
    E_BLOAD(1, KI(t + 3));
    E_ALOAD(0, KI(t + 2));
    E_COMPUTE(1, 1);
    SYNC;
    E_BSTORE(0, 0);
    SYNC;
  }
  // tail
  E_ALOAD(1, KI(NIT - 1));
  E_COMPUTE(0, 0);
  SYNC;
  E_BSTORE(1, 1);
  SYNC;
  E_COMPUTE(1, 1);

#undef E_BLOAD
#undef E_ALOAD
#undef E_BSTORE
#undef E_COMPUTE
#undef SYNC

  if constexpr (FULLEPI) {
    // epilogue: D[r][c]: c = lane&15 (e), r = (lane>>4)*4 + j  [m89-verified]
    #pragma unroll
    for (int m = 0; m < 4; ++m) {
      #pragma unroll
      for (int j = 0; j < 4; ++j) {
        const int r = wr * 64 + m * 16 + fq * 4 + j;
        if (r < ncnt) {
          const float sc = scs[r];
          float* op = outp + (size_t)(l * 256 + r) * DD + n0 + wc * 128 + fr;
          #pragma unroll
          for (int n = 0; n < 8; ++n) op[n * 16] = acc[m][n][j] * sc;
        }
      }
    }
  } else {
    float s = acc[0][0][0] + acc[1][3][1] + acc[2][5][2] + acc[3][7][3] + scs[tid & 255];
    outp[(size_t)bid * 512 + tid] = s;
  }
}

// ---------------- combine: lat_bf16[t][d] = sum_k selp[tpos[t*4+k]][d] ----------------
__global__ __launch_bounds__(256) void k_combine(const float* __restrict__ selp,
    const int* __restrict__ tpos, unsigned short* __restrict__ lat)
{
  const size_t i = ((size_t)blockIdx.x * 256 + threadIdx.x) << 2;
  const size_t t = i >> 10, d = i & 1023;
  int4 tp = *(const int4*)(tpos + (t << 2));
  float4 s0 = *(const float4*)(selp + (size_t)tp.x * DD + d);
  float4 s1 = *(const float4*)(selp + (size_t)tp.y * DD + d);
  float4 s2 = *(const float4*)(selp + (size_t)tp.z * DD + d);
  float4 s3 = *(const float4*)(selp + (size_t)tp.w * DD + d);
  float r0 = s0.x + s1.x + s2.x + s3.x;
  float r1 = s0.y + s1.y + s2.y + s3.y;
  float r2 = s0.z + s1.z + s2.z + s3.z;
  float r3 = s0.w + s1.w + s2.w + s3.w;
  uint2 pk; pk.x = pack2(r0, r1); pk.y = pack2(r2, r3);
  *(uint2*)(lat + i) = pk;
}

// ---------------- out_proj: y = x + lat @ out_w^T + b  (BM=128,BN=64, reg-staged dbuf) ----------------
__global__ __launch_bounds__(256, 2) void k_outproj(
    const unsigned short* __restrict__ lat, const float* __restrict__ W2,
    const float* __restrict__ xres, const float* __restrict__ bias,
    float* __restrict__ y)
{
  const int n0 = blockIdx.x * 64;
  const int m0 = blockIdx.y * 128;
  const int tid = threadIdx.x, lane = tid & 63, wid = tid >> 6;

  __shared__ alignas(16) unsigned short As[2][128][40];
  __shared__ alignas(16) unsigned short Bs[2][64][40];

  const int aq = tid >> 2, aseg = tid & 3;
  const unsigned short* la0 = lat + (size_t)(m0 + aq) * DD + aseg * 8;
  const unsigned short* la1 = lat + (size_t)(m0 + aq + 64) * DD + aseg * 8;
  const int be = tid >> 2, bks = tid & 3;
  const float* wb = W2 + (size_t)(n0 + be) * DD + bks * 8;

  f32x4 acc[2][4];
  #pragma unroll
  for (int m = 0; m < 2; ++m)
    #pragma unroll
    for (int n = 0; n < 4; ++n)
      #pragma unroll
      for (int j = 0; j < 4; ++j) acc[m][n][j] = 0.f;

  int4 av0, av1;
  float4 w0, w1;

#define O_LOAD(kk) do { \
    av0 = *(const int4*)(la0 + (kk)); \
    av1 = *(const int4*)(la1 + (kk)); \
    w0 = *(const float4*)(wb + (kk)); \
    w1 = *(const float4*)(wb + (kk) + 4); \
  } while (0)

#define O_STORE(b) do { \
    *(int4*)&As[b][aq][aseg * 8]      = av0; \
    *(int4*)&As[b][aq + 64][aseg * 8] = av1; \
    uint4 pv; \
    pv.x = pack2(w0.x, w0.y); pv.y = pack2(w0.z, w0.w); \
    pv.z = pack2(w1.x, w1.y); pv.w = pack2(w1.z, w1.w); \
    *(uint4*)&Bs[b][be][bks * 8] = pv; \
  } while (0)

  O_LOAD(0); O_STORE(0); __syncthreads();
  int cur = 0;
  for (int t = 0; t < 32; ++t) {
    const bool more = (t < 31);
    if (more) O_LOAD((t + 1) * 32);
    short8 af[2], bf[4];
    #pragma unroll
    for (int n = 0; n < 4; ++n)
      bf[n] = *(const short8*)&Bs[cur][n * 16 + (lane & 15)][(lane >> 4) * 8];
    #pragma unroll
    for (int m = 0; m < 2; ++m)
      af[m] = *(const short8*)&As[cur][wid * 32 + m * 16 + (lane & 15)][(lane >> 4) * 8];
    #pragma unroll
    for (int m = 0; m < 2; ++m)
      #pragma unroll
      for (int n = 0; n < 4; ++n)
        acc[m][n] = __builtin_amdgcn_mfma_f32_16x16x32_bf16(af[m], bf[n], acc[m][n], 0, 0, 0);
    if (more) O_STORE(cur ^ 1);
    __syncthreads();
    cur ^= 1;
  }
#undef O_LOAD
#undef O_STORE

  #pragma unroll
  for (int m = 0; m < 2; ++m) {
    #pragma unroll
    for (int j = 0; j < 4; ++j) {
      const int t = m0 + wid * 32 + m * 16 + ((lane >> 4) << 2) + j;
      #pragma unroll
      for (int n = 0; n < 4; ++n) {
        const int e = n0 + n * 16 + (lane & 15);
        y[(size_t)t * DD + e] = xres[(size_t)t * DD + e] + acc[m][n][j] + bias[e];
      }
    }
  }
}

// ---------------- LayerNorm ----------------
__global__ __launch_bounds__(256) void k_ln(const float* __restrict__ y,
    const float* __restrict__ g, const float* __restrict__ b, float* __restrict__ out)
{
  const int t = blockIdx.x, tid = threadIdx.x;
  float4 v = *(const float4*)(y + (size_t)t * DD + tid * 4);
  float s  = v.x + v.y + v.z + v.w;
  float ss = v.x*v.x + v.y*v.y + v.z*v.z + v.w*v.w;
  #pragma unroll
  for (int off = 32; off; off >>= 1) { s += __shfl_down(s, off); ss += __shfl_down(ss, off); }
  __shared__ float rs[8];
  const int wid = tid >> 6, lane = tid & 63;
  if (lane == 0) { rs[wid] = s; rs[wid + 4] = ss; }
  __syncthreads();
  float S  = rs[0] + rs[1] + rs[2] + rs[3];
  float SS = rs[4] + rs[5] + rs[6] + rs[7];
  float mu = S * (1.0f / DD);
  float var = SS * (1.0f / DD) - mu * mu;
  float inv = rsqrtf(var + 1e-5f);
  float4 gg = *(const float4*)(g + tid * 4);
  float4 bb = *(const float4*)(b + tid * 4);
  float4 o;
  o.x = gg.x * (v.x - mu) * inv + bb.x;
  o.y = gg.y * (v.y - mu) * inv + bb.y;
  o.z = gg.z * (v.z - mu) * inv + bb.z;
  o.w = gg.w * (v.w - mu) * inv + bb.w;
  *(float4*)(out + (size_t)t * DD + tid * 4) = o;
}

extern "C" void kernel_launch(void* const* d_in, const int* in_sizes, int n_in,
                              void* d_out, int out_size, void* d_ws, size_t ws_size,
                              hipStream_t stream) {
  (void)in_sizes; (void)n_in; (void)out_size;
  const float* x   = (const float*)d_in[0];
  const float* gw  = (const float*)d_in[1];
  const float* lw  = (const float*)d_in[2];
  const float* ow  = (const float*)d_in[3];
  const float* obv = (const float*)d_in[4];
  const float* lng = (const float*)d_in[5];
  const float* lnb = (const float*)d_in[6];
  float* out = (float*)d_out;
  char* ws = (char*)d_ws;

  // layout: xg 24MB | selp 48MB+4KB | lat 4MB | y 8MB | counts | bscore | tpos | probe @100MB
  unsigned short* xg     = (unsigned short*)(ws);
  float*          selp   = (float*)(ws + (24ull << 20));
  unsigned short* lat    = (unsigned short*)(ws + (73ull << 20));
  float*          y      = (float*)(ws + (77ull << 20));
  int*            counts = (int*)(ws + (85ull << 20));
  float*          bscore = (float*)(ws + (85ull << 20) + 4096);
  int*            tpos   = (int*)(ws + (86ull << 20));
  float*          probe  = (float*)(ws + (100ull << 20));
  if (ws_size < (101ull << 20)) return;   // loud failure

  hipMemsetAsync(counts, 0, LL * sizeof(int), stream);
  hipMemsetAsync(selp + (size_t)SENT * DD, 0, DD * sizeof(float), stream);  // sentinel row
  k_gate<<<TT / 8, 256, 0, stream>>>(x, gw, xg, counts, bscore, tpos);
  k_expert_t<15, 32><<<192, 512, 0, stream>>>(xg, lw, counts, bscore, selp);  // REAL
  k_combine<<<TT * DD / (256 * 4), 256, 0, stream>>>(selp, tpos, lat);
  k_outproj<<<dim3(16, 16), 256, 0, stream>>>(lat, ow, x, obv, y);
  k_ln<<<TT, 256, 0, stream>>>(y, lng, lnb, out);

  // ---- diagnostic probes (outputs unused; NIT=64 so they rank above ~115us fills) ----
  k_expert_t<11, 64><<<192, 512, 0, stream>>>(xg, lw, counts, bscore, probe);  // no MFMA
  k_expert_t<13, 64><<<192, 512, 0, stream>>>(xg, lw, counts, bscore, probe);  // no LDS ops
  k_expert_t<14, 64><<<192, 512, 0, stream>>>(xg, lw, counts, bscore, probe);  // no global loads
  k_expert_t< 7, 64><<<192, 512, 0, stream>>>(xg, lw, counts, bscore, probe);  // no barriers
}

// Round 12
// 249.331 us; speedup vs baseline: 1.9255x; 1.9255x over previous
//
#include <hip/hip_runtime.h>
#include <stdint.h>

// HyperLatticeBlock: B=2,S=1024,D=1024,L=48,K=4  (tokens T=2048)
// gate(top4+swizzled A-pack) -> wconv(W->Wt bf16 swizzled) -> 4-phase m201-style expert GEMM
//   -> combine -> out_proj -> LN
#define TT 2048
#define DD 1024
#define LL 48
#define SENT (LL * 256)   // sentinel selp row (zeroed)

typedef __attribute__((ext_vector_type(8))) short short8;
typedef __attribute__((ext_vector_type(4))) float f32x4;

static __device__ __forceinline__ unsigned int f2bf(float f) {
  union { float f; unsigned int u; } v; v.f = f;
  return (v.u + 0x7FFFu + ((v.u >> 16) & 1u)) >> 16;   // RNE f32->bf16 bits
}
static __device__ __forceinline__ unsigned int pack2(float a, float b) {
  return f2bf(a) | (f2bf(b) << 16);
}

typedef __attribute__((address_space(1))) const void* as1_t;
typedef __attribute__((address_space(3))) void* as3_t;
static __device__ __forceinline__ void gll16(const void* g, void* s) {
  __builtin_amdgcn_global_load_lds((as1_t)g, (as3_t)s, 16, 0, 0);
}

#define LGKM0 do { asm volatile("s_waitcnt lgkmcnt(0)" ::: "memory"); \
                   __builtin_amdgcn_sched_barrier(0); } while (0)
#define VM0   do { asm volatile("s_waitcnt vmcnt(0)" ::: "memory"); \
                   __builtin_amdgcn_sched_barrier(0); } while (0)
#define BAR   do { __builtin_amdgcn_s_barrier(); __builtin_amdgcn_sched_barrier(0); } while (0)

// ---------------- gate: logits fp32, top-4, softmax, bucket scatter + swizzled A-pack ----------------
// xg row layout: 16 chunks (64 k each) x 8 16B-units; logical unit v stored at physical v^(row&7).
__global__ __launch_bounds__(256) void k_gate(
    const float* __restrict__ x, const float* __restrict__ gw,
    unsigned short* __restrict__ xg, int* __restrict__ counts,
    float* __restrict__ bscore, int* __restrict__ tpos)
{
  __shared__ float xs[8][1024];
  __shared__ float lg[8][48];
  __shared__ int tp_s[32];
  const int tid = threadIdx.x;
  const int t0 = blockIdx.x * 8;
  for (int u = tid; u < 2048; u += 256) {
    int tok = u >> 8;
    int c = (u & 255) << 2;
    float4 v = *(const float4*)(x + (size_t)(t0 + tok) * DD + c);
    *(float4*)&xs[tok][c] = v;
  }
  __syncthreads();
  const int lane = tid & 63, wid = tid >> 6;
  for (int li = 0; li < 12; ++li) {
    const int l = wid + (li << 2);
    const float4* gp = (const float4*)(gw + (size_t)l * DD);
    float4 g0 = gp[lane], g1 = gp[lane + 64], g2 = gp[lane + 128], g3 = gp[lane + 192];
    for (int tok = 0; tok < 8; ++tok) {
      const float4* xp = (const float4*)&xs[tok][0];
      float4 a0 = xp[lane], a1 = xp[lane + 64], a2 = xp[lane + 128], a3 = xp[lane + 192];
      float s = a0.x*g0.x + a0.y*g0.y + a0.z*g0.z + a0.w*g0.w
              + a1.x*g1.x + a1.y*g1.y + a1.z*g1.z + a1.w*g1.w
              + a2.x*g2.x + a2.y*g2.y + a2.z*g2.z + a2.w*g2.w
              + a3.x*g3.x + a3.y*g3.y + a3.z*g3.z + a3.w*g3.w;
      #pragma unroll
      for (int off = 32; off; off >>= 1) s += __shfl_down(s, off);
      if (lane == 0) lg[tok][l] = s;
    }
  }
  __syncthreads();
  if (tid < 8) {
    const int tok = tid;
    float v[4]; int id[4];
    unsigned long long taken = 0ull;
    for (int k = 0; k < 4; ++k) {
      float best = -3.4e38f; int bi = 0;
      for (int l = 0; l < 48; ++l) {
        float cand = lg[tok][l];
        if (!((taken >> l) & 1ull) && cand > best) { best = cand; bi = l; }
      }
      taken |= (1ull << bi); v[k] = best; id[k] = bi;
    }
    float e1 = expf(v[1] - v[0]);
    float e2 = expf(v[2] - v[0]);
    float e3 = expf(v[3] - v[0]);
    float inv = 1.0f / (1.0f + e1 + e2 + e3);
    float sc[4] = { inv, e1*inv, e2*inv, e3*inv };
    for (int k = 0; k < 4; ++k) {
      int pos = atomicAdd(&counts[id[k]], 1);
      bscore[id[k] * TT + pos] = sc[k];
      int dst = (pos < 256) ? (id[k] * 256 + pos) : SENT;
      tp_s[tok * 4 + k] = dst;
      tpos[((t0 + tok) << 2) | k] = dst;
    }
  }
  __syncthreads();
  {
    const int c = tid >> 4, v = (tid >> 1) & 7, h = tid & 1;
    for (int g = 0; g < 32; ++g) {
      int dst = tp_s[g];
      if (dst == SENT) continue;
      const float* src = xs[g >> 2];
      float a0 = src[tid*4], a1 = src[tid*4+1], a2 = src[tid*4+2], a3 = src[tid*4+3];
      uint2 pk; pk.x = pack2(a0, a1); pk.y = pack2(a2, a3);
      const int p = v ^ (dst & 7);
      *(uint2*)(xg + (size_t)dst * DD + c * 64 + p * 8 + h * 4) = pk;
    }
  }
}

// ---------------- wconv: Wt[l][e][d] bf16 (swizzled units) <- W[l][d][e] f32, 128x128 tiles ----------
// Output row layout matches xg: per 64-d chunk, logical unit v at physical v^(e&7).
__global__ __launch_bounds__(256) void k_wconv(const float* __restrict__ W,
                                               unsigned short* __restrict__ Wt)
{
  const int l = blockIdx.z, d0 = blockIdx.y * 128, e0 = blockIdx.x * 128;
  __shared__ unsigned short T[128][136];
  const float* src = W + (size_t)l * DD * DD;
  const int tid = threadIdx.x;
  #pragma unroll
  for (int i = 0; i < 16; ++i) {
    int fl = i * 256 + tid;
    int d = fl >> 5, e4 = fl & 31;
    float4 v = *(const float4*)(src + (size_t)(d0 + d) * DD + e0 + e4 * 4);
    #pragma unroll
    for (int j = 0; j < 4; ++j) {
      int e = e4 * 4 + j;
      int unit = (d >> 3) ^ (e & 7);
      float fv = (j == 0) ? v.x : (j == 1) ? v.y : (j == 2) ? v.z : v.w;
      T[e][unit * 8 + (d & 7)] = (unsigned short)f2bf(fv);
    }
  }
  __syncthreads();
  #pragma unroll
  for (int i2 = 0; i2 < 8; ++i2) {
    int uo = i2 * 256 + tid;
    int e = uo >> 4, ds = uo & 15;
    short8 s8 = *(const short8*)&T[e][(ds ^ (e & 7)) * 8];   // logical d-octet ds
    int od = d0 + (ds >> 3) * 64 + (((ds & 7) ^ (e & 7)) * 8);
    *(short8*)(Wt + ((size_t)l << 20) + (size_t)(e0 + e) * DD + od) = s8;
  }
}

// ---------------- expert GEMM: m201-style. BM=256, BN=256, BK=64, 512 thr (2M x 4N waves) ----------
// LDS 128KB dbuf; staging all gll16 (linear, pre-swizzled sources); frag reads ds_read_b128 2-way.
// 4 phases/K-step: {2 gll16 | 4-8 b128 reads | lgkm0 | setprio(1) 16 MFMA setprio(0)}.
// One vmcnt(0)+barrier per K-step (staging issued >=3 phases earlier -> tail-only drain).
__global__ __launch_bounds__(512, 1) void k_expert(
    const unsigned short* __restrict__ xg, const unsigned short* __restrict__ Wt,
    const int* __restrict__ counts, const float* __restrict__ bscore,
    float* __restrict__ selp)
{
  const int bid = blockIdx.x;
  const int l = bid % LL;                 // expert-major: 4 n-blocks of l share an XCD (bid%8)
  const int n0 = (bid / LL) * 256;
  const int ncnt = min(counts[l], 256);
  const int tid = threadIdx.x, lane = tid & 63, wid = tid >> 6;
  const int mh = wid & 1, nq = wid >> 1;  // 2M x 4N; per-wave output 128 x 64
  const int fr = lane & 15, fq = lane >> 4;

  __shared__ unsigned short As[2][256][64];   // 64 KB
  __shared__ unsigned short Bs[2][256][64];   // 64 KB
  __shared__ float scs[256];
  if (tid < 256) scs[tid] = (tid < ncnt) ? bscore[l * TT + tid] : 0.f;

  // staging geometry: unit u = i*512+tid -> row = i*64 + (tid>>3), phys slot p = tid&7 (linear copy)
  const int srow = tid >> 3, sp = tid & 7;
  const unsigned short* ax = xg + ((size_t)l << 18) + sp * 8;
  const unsigned short* bx = Wt + ((size_t)l << 20) + (size_t)n0 * DD + sp * 8;
  size_t soff[4]; int loff[4];
  #pragma unroll
  for (int i = 0; i < 4; ++i) {
    const int row = i * 64 + srow;
    soff[i] = (size_t)row * DD;
    loff[i] = row * 64 + sp * 8;
  }

  // frag-read swizzle: slot s = kh*4+fq stored at phys s^(row&7); row&7 == fr&7 for all frag rows
  const int sw0 = ((fq ^ (fr & 7)) << 3);
  const int sw1 = sw0 ^ 32;

  f32x4 acc[8][4];
  #pragma unroll
  for (int m = 0; m < 8; ++m)
    #pragma unroll
    for (int n = 0; n < 4; ++n)
      #pragma unroll
      for (int j = 0; j < 4; ++j) acc[m][n][j] = 0.f;

  short8 bf[4];

#define STG_A(i, nb, tc) gll16(ax + soff[i] + (tc) * 64, (unsigned short*)&As[nb][0][0] + loff[i])
#define STG_B(i, nb, tc) gll16(bx + soff[i] + (tc) * 64, (unsigned short*)&Bs[nb][0][0] + loff[i])

#define RDB(bb, sw) do { \
    _Pragma("unroll") for (int n = 0; n < 4; ++n) \
      bf[n] = *(const short8*)&Bs[bb][nq * 64 + n * 16 + fr][sw]; } while (0)

#define PHASE(bb, sw, mg, EXTRA) do { \
    short8 a0 = *(const short8*)&As[bb][mh * 128 + ((mg)*4+0) * 16 + fr][sw]; \
    short8 a1 = *(const short8*)&As[bb][mh * 128 + ((mg)*4+1) * 16 + fr][sw]; \
    short8 a2 = *(const short8*)&As[bb][mh * 128 + ((mg)*4+2) * 16 + fr][sw]; \
    short8 a3 = *(const short8*)&As[bb][mh * 128 + ((mg)*4+3) * 16 + fr][sw]; \
    EXTRA; \
    LGKM0; \
    __builtin_amdgcn_s_setprio(1); \
    _Pragma("unroll") for (int n = 0; n < 4; ++n) { \
      acc[(mg)*4+0][n] = __builtin_amdgcn_mfma_f32_16x16x32_bf16(a0, bf[n], acc[(mg)*4+0][n], 0, 0, 0); \
      acc[(mg)*4+1][n] = __builtin_amdgcn_mfma_f32_16x16x32_bf16(a1, bf[n], acc[(mg)*4+1][n], 0, 0, 0); \
      acc[(mg)*4+2][n] = __builtin_amdgcn_mfma_f32_16x16x32_bf16(a2, bf[n], acc[(mg)*4+2][n], 0, 0, 0); \
      acc[(mg)*4+3][n] = __builtin_amdgcn_mfma_f32_16x16x32_bf16(a3, bf[n], acc[(mg)*4+3][n], 0, 0, 0); \
    } \
    __builtin_amdgcn_s_setprio(0); \
  } while (0)

  // prologue: stage tile 0 into buffer 0
  #pragma unroll
  for (int i = 0; i < 4; ++i) STG_A(i, 0, 0);
  #pragma unroll
  for (int i = 0; i < 4; ++i) STG_B(i, 0, 0);
  VM0; BAR;

  int b = 0;
  for (int t = 0; t < 16; ++t) {
    const int nb = b ^ 1, tc = t + 1;
    const bool pre = (t < 15);
    RDB(b, sw0);
    PHASE(b, sw0, 0, { if (pre) { STG_A(0, nb, tc); STG_A(1, nb, tc); } });
    PHASE(b, sw0, 1, { if (pre) { STG_A(2, nb, tc); STG_A(3, nb, tc); } });
    RDB(b, sw1);
    PHASE(b, sw1, 0, { if (pre) { STG_B(0, nb, tc); STG_B(1, nb, tc); } });
    PHASE(b, sw1, 1, { if (pre) { STG_B(2, nb, tc); STG_B(3, nb, tc); } });
    if (pre) { VM0; }
    BAR;
    b = nb;
  }

#undef STG_A
#undef STG_B
#undef RDB
#undef PHASE

  // epilogue: D[r][c]: c = lane&15 (e), r = (lane>>4)*4 + j  [m89-verified]
  #pragma unroll
  for (int mf = 0; mf < 8; ++mf) {
    #pragma unroll
    for (int j = 0; j < 4; ++j) {
      const int r = mh * 128 + mf * 16 + fq * 4 + j;
      if (r < ncnt) {
        const float sc = scs[r];
        float* op = selp + (size_t)(l * 256 + r) * DD + n0 + nq * 64 + fr;
        #pragma unroll
        for (int n = 0; n < 4; ++n) op[n * 16] = acc[mf][n][j] * sc;
      }
    }
  }
}

// ---------------- combine: lat_bf16[t][d] = sum_k selp[tpos[t*4+k]][d] ----------------
__global__ __launch_bounds__(256) void k_combine(const float* __restrict__ selp,
    const int* __restrict__ tpos, unsigned short* __restrict__ lat)
{
  const size_t i = ((size_t)blockIdx.x * 256 + threadIdx.x) << 2;
  const size_t t = i >> 10, d = i & 1023;
  int4 tp = *(const int4*)(tpos + (t << 2));
  float4 s0 = *(const float4*)(selp + (size_t)tp.x * DD + d);
  float4 s1 = *(const float4*)(selp + (size_t)tp.y * DD + d);
  float4 s2 = *(const float4*)(selp + (size_t)tp.z * DD + d);
  float4 s3 = *(const float4*)(selp + (size_t)tp.w * DD + d);
  float r0 = s0.x + s1.x + s2.x + s3.x;
  float r1 = s0.y + s1.y + s2.y + s3.y;
  float r2 = s0.z + s1.z + s2.z + s3.z;
  float r3 = s0.w + s1.w + s2.w + s3.w;
  uint2 pk; pk.x = pack2(r0, r1); pk.y = pack2(r2, r3);
  *(uint2*)(lat + i) = pk;
}

// ---------------- out_proj: y = x + lat @ out_w^T + b  (BM=128,BN=64, reg-staged dbuf) ----------------
__global__ __launch_bounds__(256, 2) void k_outproj(
    const unsigned short* __restrict__ lat, const float* __restrict__ W2,
    const float* __restrict__ xres, const float* __restrict__ bias,
    float* __restrict__ y)
{
  const int n0 = blockIdx.x * 64;
  const int m0 = blockIdx.y * 128;
  const int tid = threadIdx.x, lane = tid & 63, wid = tid >> 6;

  __shared__ alignas(16) unsigned short As[2][128][40];
  __shared__ alignas(16) unsigned short Bs[2][64][40];

  const int aq = tid >> 2, aseg = tid & 3;
  const unsigned short* la0 = lat + (size_t)(m0 + aq) * DD + aseg * 8;
  const unsigned short* la1 = lat + (size_t)(m0 + aq + 64) * DD + aseg * 8;
  const int be = tid >> 2, bks = tid & 3;
  const float* wb = W2 + (size_t)(n0 + be) * DD + bks * 8;

  f32x4 acc[2][4];
  #pragma unroll
  for (int m = 0; m < 2; ++m)
    #pragma unroll
    for (int n = 0; n < 4; ++n)
      #pragma unroll
      for (int j = 0; j < 4; ++j) acc[m][n][j] = 0.f;

  int4 av0, av1;
  float4 w0, w1;

#define O_LOAD(kk) do { \
    av0 = *(const int4*)(la0 + (kk)); \
    av1 = *(const int4*)(la1 + (kk)); \
    w0 = *(const float4*)(wb + (kk)); \
    w1 = *(const float4*)(wb + (kk) + 4); \
  } while (0)

#define O_STORE(b) do { \
    *(int4*)&As[b][aq][aseg * 8]      = av0; \
    *(int4*)&As[b][aq + 64][aseg * 8] = av1; \
    uint4 pv; \
    pv.x = pack2(w0.x, w0.y); pv.y = pack2(w0.z, w0.w); \
    pv.z = pack2(w1.x, w1.y); pv.w = pack2(w1.z, w1.w); \
    *(uint4*)&Bs[b][be][bks * 8] = pv; \
  } while (0)

  O_LOAD(0); O_STORE(0); __syncthreads();
  int cur = 0;
  for (int t = 0; t < 32; ++t) {
    const bool more = (t < 31);
    if (more) O_LOAD((t + 1) * 32);
    short8 af[2], bf[4];
    #pragma unroll
    for (int n = 0; n < 4; ++n)
      bf[n] = *(const short8*)&Bs[cur][n * 16 + (lane & 15)][(lane >> 4) * 8];
    #pragma unroll
    for (int m = 0; m < 2; ++m)
      af[m] = *(const short8*)&As[cur][wid * 32 + m * 16 + (lane & 15)][(lane >> 4) * 8];
    #pragma unroll
    for (int m = 0; m < 2; ++m)
      #pragma unroll
      for (int n = 0; n < 4; ++n)
        acc[m][n] = __builtin_amdgcn_mfma_f32_16x16x32_bf16(af[m], bf[n], acc[m][n], 0, 0, 0);
    if (more) O_STORE(cur ^ 1);
    __syncthreads();
    cur ^= 1;
  }
#undef O_LOAD
#undef O_STORE

  #pragma unroll
  for (int m = 0; m < 2; ++m) {
    #pragma unroll
    for (int j = 0; j < 4; ++j) {
      const int t = m0 + wid * 32 + m * 16 + ((lane >> 4) << 2) + j;
      #pragma unroll
      for (int n = 0; n < 4; ++n) {
        const int e = n0 + n * 16 + (lane & 15);
        y[(size_t)t * DD + e] = xres[(size_t)t * DD + e] + acc[m][n][j] + bias[e];
      }
    }
  }
}

// ---------------- LayerNorm ----------------
__global__ __launch_bounds__(256) void k_ln(const float* __restrict__ y,
    const float* __restrict__ g, const float* __restrict__ b, float* __restrict__ out)
{
  const int t = blockIdx.x, tid = threadIdx.x;
  float4 v = *(const float4*)(y + (size_t)t * DD + tid * 4);
  float s  = v.x + v.y + v.z + v.w;
  float ss = v.x*v.x + v.y*v.y + v.z*v.z + v.w*v.w;
  #pragma unroll
  for (int off = 32; off; off >>= 1) { s += __shfl_down(s, off); ss += __shfl_down(ss, off); }
  __shared__ float rs[8];
  const int wid = tid >> 6, lane = tid & 63;
  if (lane == 0) { rs[wid] = s; rs[wid + 4] = ss; }
  __syncthreads();
  float S  = rs[0] + rs[1] + rs[2] + rs[3];
  float SS = rs[4] + rs[5] + rs[6] + rs[7];
  float mu = S * (1.0f / DD);
  float var = SS * (1.0f / DD) - mu * mu;
  float inv = rsqrtf(var + 1e-5f);
  float4 gg = *(const float4*)(g + tid * 4);
  float4 bb = *(const float4*)(b + tid * 4);
  float4 o;
  o.x = gg.x * (v.x - mu) * inv + bb.x;
  o.y = gg.y * (v.y - mu) * inv + bb.y;
  o.z = gg.z * (v.z - mu) * inv + bb.z;
  o.w = gg.w * (v.w - mu) * inv + bb.w;
  *(float4*)(out + (size_t)t * DD + tid * 4) = o;
}

extern "C" void kernel_launch(void* const* d_in, const int* in_sizes, int n_in,
                              void* d_out, int out_size, void* d_ws, size_t ws_size,
                              hipStream_t stream) {
  (void)in_sizes; (void)n_in; (void)out_size;
  const float* x   = (const float*)d_in[0];
  const float* gw  = (const float*)d_in[1];
  const float* lw  = (const float*)d_in[2];
  const float* ow  = (const float*)d_in[3];
  const float* obv = (const float*)d_in[4];
  const float* lng = (const float*)d_in[5];
  const float* lnb = (const float*)d_in[6];
  float* out = (float*)d_out;
  char* ws = (char*)d_ws;

  // layout: xg 24MB @0 | selp 48MB+4K @24M | lat @73M | y @77M | counts @85M | bscore | tpos @86M
  //         Wt 96MB @96M..192M
  unsigned short* xg     = (unsigned short*)(ws);
  float*          selp   = (float*)(ws + (24ull << 20));
  unsigned short* lat    = (unsigned short*)(ws + (73ull << 20));
  float*          y      = (float*)(ws + (77ull << 20));
  int*            counts = (int*)(ws + (85ull << 20));
  float*          bscore = (float*)(ws + (85ull << 20) + 4096);
  int*            tpos   = (int*)(ws + (86ull << 20));
  unsigned short* Wt     = (unsigned short*)(ws + (96ull << 20));
  if (ws_size < (193ull << 20)) return;   // loud failure

  hipMemsetAsync(counts, 0, LL * sizeof(int), stream);
  hipMemsetAsync(selp + (size_t)SENT * DD, 0, DD * sizeof(float), stream);  // sentinel row
  k_gate<<<TT / 8, 256, 0, stream>>>(x, gw, xg, counts, bscore, tpos);
  k_wconv<<<dim3(8, 8, LL), 256, 0, stream>>>(lw, Wt);
  k_expert<<<192, 512, 0, stream>>>(xg, Wt, counts, bscore, selp);
  k_combine<<<TT * DD / (256 * 4), 256, 0, stream>>>(selp, tpos, lat);
  k_outproj<<<dim3(16, 16), 256, 0, stream>>>(lat, ow, x, obv, y);
  k_ln<<<TT, 256, 0, stream>>>(y, lng, lnb, out);
}